// Round 3
// baseline (10.158 us; speedup 1.0000x reference)
//
#include <hip/hip_runtime.h>
#include <math.h>

// Problem constants (fixed by reference setup_inputs)
#define B_N   16
#define W_IN  64
#define H_IN  64
#define C_IN  8
#define D_OUT 4
#define NXo   63
#define NYo   63
#define NPOS  (B_N * NXo * NYo)   // 63504 output positions; out has ×4 d-broadcast

// Analytic collapse of the QCNN circuit:
// CZPow is diagonal; CXPow(e) is block-diagonal in its first (control) qubit.
// Qubit 0 (the measured one) is the preserved qubit of gate pairs (0,1) and
// (0,2), and pair (2,3) doesn't touch it. Hence P(q0) is invariant under the
// whole learned circuit and <Z0> = cos(pi * a0), a0 = x[b,i,j,c].
// out[b,i,j,d] = arccos(clip(sum_c cos(pi*x[b,i,j,c]), -1+1e-5, 1-1e-5)) / pi
// for every d (kernel weights cancel in the forward pass).
//
// cos(pi*a) with a in [0,1) -> hardware v_cos_f32 (cos(2*pi*x), revolutions)
// at x = 0.5*a in [0,0.5): no range reduction needed, ~1 ulp in this range.

static __device__ __forceinline__ float hw_cos_rev(float x) {
    float r;
    asm volatile("v_cos_f32 %0, %1" : "=v"(r) : "v"(x));
    return r;
}

__global__ __launch_bounds__(256) void qconv_kernel(const float* __restrict__ x,
                                                    float* __restrict__ out) {
    constexpr float PI_F = 3.14159265358979323846f;
    int gid = blockIdx.x * blockDim.x + threadIdx.x;
    if (gid >= NPOS) return;

    int j = gid % NYo;
    int t = gid / NYo;
    int i = t % NXo;
    int b = t / NXo;

    // x[b][i][j][0..7]: contiguous 8 floats, 32B-aligned
    const float4* p = (const float4*)(x + ((b * W_IN + i) * H_IN + j) * C_IN);
    float4 lo = p[0];
    float4 hi = p[1];

    float c0 = hw_cos_rev(0.5f * lo.x);
    float c1 = hw_cos_rev(0.5f * lo.y);
    float c2 = hw_cos_rev(0.5f * lo.z);
    float c3 = hw_cos_rev(0.5f * lo.w);
    float c4 = hw_cos_rev(0.5f * hi.x);
    float c5 = hw_cos_rev(0.5f * hi.y);
    float c6 = hw_cos_rev(0.5f * hi.z);
    float c7 = hw_cos_rev(0.5f * hi.w);

    // pairwise tree sum (short dependent chain)
    float s = ((c0 + c1) + (c2 + c3)) + ((c4 + c5) + (c6 + c7));

    float v = fminf(fmaxf(s, -1.0f + 1e-5f), 1.0f - 1e-5f);
    float r = acosf(v) * (1.0f / PI_F);

    // out[b][i][j][d] for d=0..3 — identical along d; 16B-aligned float4 store
    ((float4*)out)[gid] = make_float4(r, r, r, r);
}

extern "C" void kernel_launch(void* const* d_in, const int* in_sizes, int n_in,
                              void* d_out, int out_size, void* d_ws, size_t ws_size,
                              hipStream_t stream) {
    const float* x = (const float*)d_in[0];   // [16,64,64,8] f32
    float* out = (float*)d_out;               // [16,63,63,4] f32

    int blocks = (NPOS + 255) / 256;
    qconv_kernel<<<blocks, 256, 0, stream>>>(x, out);
}